// Round 1
// 280.416 us; speedup vs baseline: 1.0111x; 1.0111x over previous
//
#include <hip/hip_runtime.h>
#include <math.h>

#define B_ 4
#define C_ 256
#define CI_ 128
#define N_ 4096
#define QT_ 128
#define KT_ 64
#define KH_ 2048
#define NITER (KH_ / KT_)     // 32
#define KSTRIDE 264   // 256 + 8 pad (verified round 3)
#define VSTRIDE 72    // 64 + 8 pad (verified round 3)
constexpr float EPS_ = 1e-5f;

typedef __attribute__((ext_vector_type(8))) short bfrag;
typedef __attribute__((ext_vector_type(4))) float f4;
typedef __attribute__((ext_vector_type(16))) float facc16;

__device__ __forceinline__ unsigned short bf16r(float x) {
    unsigned u = __float_as_uint(x);
    u += 0x7FFFu + ((u >> 16) & 1u);
    return (unsigned short)(u >> 16);
}
__device__ __forceinline__ unsigned pack_bf16(float a, float b) {
    unsigned ua = __float_as_uint(a); ua += 0x7FFFu + ((ua >> 16) & 1u);
    unsigned ub = __float_as_uint(b); ub += 0x7FFFu + ((ub >> 16) & 1u);
    return (ua >> 16) | (ub & 0xFFFF0000u);
}

// ---------------- K1: x -> xt bf16 [b][n][c]; block(0,0,0) zeroes sums ---
__global__ __launch_bounds__(256) void make_xt(const float* __restrict__ x,
                                               unsigned short* __restrict__ xt,
                                               float* __restrict__ sums) {
    if (blockIdx.x == 0 && blockIdx.y == 0 && blockIdx.z == 0) {
        sums[threadIdx.x] = 0.f;
        sums[threadIdx.x + 256] = 0.f;
    }
    int n  = blockIdx.x * 256 + threadIdx.x;
    int c0 = blockIdx.y * 8;
    int b  = blockIdx.z;
    const float* xb = x + (size_t)b * C_ * N_;
    unsigned short buf[8];
#pragma unroll
    for (int c = 0; c < 8; c++) buf[c] = bf16r(xb[(c0 + c) * N_ + n]);   // coalesced
    uint4 v;
    v.x = buf[0] | ((unsigned)buf[1] << 16);
    v.y = buf[2] | ((unsigned)buf[3] << 16);
    v.z = buf[4] | ((unsigned)buf[5] << 16);
    v.w = buf[6] | ((unsigned)buf[7] << 16);
    *(uint4*)&xt[((size_t)b * N_ + n) * C_ + c0] = v;
}

// ---------------- K2: g conv (verbatim) ----------------------------------
__global__ __launch_bounds__(256) void gconv(const float* __restrict__ x,
                                             const float* __restrict__ gw,
                                             const float* __restrict__ gb,
                                             unsigned short* __restrict__ gx) {
    int m  = blockIdx.x * 256 + threadIdx.x;
    int o0 = blockIdx.y * 16;
    int b  = blockIdx.z;
    const float* xb = x + (size_t)b * C_ * N_;
    float acc[16];
#pragma unroll
    for (int o = 0; o < 16; o++) acc[o] = gb[o0 + o];
    for (int c0 = 0; c0 < C_; c0 += 8) {
        float xv[8];
#pragma unroll
        for (int j = 0; j < 8; j++) xv[j] = xb[(c0 + j) * N_ + m];
#pragma unroll
        for (int o = 0; o < 16; o++) {
            const float* wr = gw + (size_t)(o0 + o) * C_ + c0;
#pragma unroll
            for (int j = 0; j < 8; j++) acc[o] += wr[j] * xv[j];
        }
    }
#pragma unroll
    for (int o = 0; o < 16; o++)
        gx[((size_t)b * CI_ + o0 + o) * N_ + m] = bf16r(acc[o]);
}

// ---------------- K3: MFMA flash attention — 512 thr, 32x32x16 MFMA ------
// 8 waves = 4 q-bands(32q) x 2 m-groups(32m of KT=64). Each wave: 16 MFMA
// for S (32m x 32q x 256k) + 8 MFMA for PV (128ci x 32q x 32m). 32x32x16
// halves LDS operand bytes/FLOP vs 16x16x32 (16B/lane feeds 32 KFLOP).
// Same split-K(half) + m-group merge algebra, double-buffered K/V staging,
// single barrier per iter, 2-tile-deep global prefetch.
__global__ __launch_bounds__(512, 2) void attn(const unsigned short* __restrict__ xt,
                                               const unsigned short* __restrict__ gx,
                                               float* __restrict__ Yp,
                                               float* __restrict__ ml) {
    __shared__ __align__(16) unsigned short Ks[2][64 * KSTRIDE];    // 2 x 33 KB
    __shared__ __align__(16) unsigned short Vs[2][128 * VSTRIDE];   // 2 x 18 KB
    __shared__ __align__(16) unsigned short Ps[128 * VSTRIDE];      // 18 KB

    const int tid  = threadIdx.x;
    const int lane = tid & 63, w = tid >> 6;     // w in 0..7
    const int wq = w & 3, g = w >> 2;            // q-band(32), m-group
    const int col = lane & 31, h = lane >> 5;    // 32x32 frag coords
    const int half = blockIdx.x & 1;
    const int b    = (blockIdx.x & 7) >> 1;
    const int qt   = blockIdx.x >> 3;
    const int n0   = qt * QT_;
    const int kbase = half * KH_;
    const unsigned short* xtb = xt + (size_t)b * N_ * C_;
    const unsigned short* gxb = gx + (size_t)b * CI_ * N_;

    // Q B-frags: q rows n0 + 32*wq + col, 16 k-chunks of 16 (64 VGPR)
    bfrag qb[16];
#pragma unroll
    for (int kc = 0; kc < 16; kc++)
        qb[kc] = *(const bfrag*)(xtb + (size_t)(n0 + 32 * wq + col) * C_ + kc * 16 + h * 8);

    facc16 yacc[4];        // y[ci 128][q 32]: 4 ci-tiles x 16 f32
#pragma unroll
    for (int t = 0; t < 4; t++)
#pragma unroll
        for (int r = 0; r < 16; r++) yacc[t][r] = 0.f;
    float mrun = -INFINITY, lrun = 0.f;

    // prologue: tile0 -> regs -> buf0; tile1 -> regs
    uint4 kreg[4], vreg[2];
#pragma unroll
    for (int r = 0; r < 4; r++) {
        int idx = r * 512 + tid;
        kreg[r] = *(const uint4*)(xtb + (size_t)(kbase + (idx >> 5)) * C_ + (idx & 31) * 8);
    }
#pragma unroll
    for (int r = 0; r < 2; r++) {
        int idx = r * 512 + tid;
        vreg[r] = *(const uint4*)(gxb + (size_t)(idx >> 3) * N_ + kbase + (idx & 7) * 8);
    }
#pragma unroll
    for (int r = 0; r < 4; r++) {
        int idx = r * 512 + tid;
        *(uint4*)&Ks[0][(idx >> 5) * KSTRIDE + (idx & 31) * 8] = kreg[r];
    }
#pragma unroll
    for (int r = 0; r < 2; r++) {
        int idx = r * 512 + tid;
        *(uint4*)&Vs[0][(idx >> 3) * VSTRIDE + (idx & 7) * 8] = vreg[r];
    }
#pragma unroll
    for (int r = 0; r < 4; r++) {
        int idx = r * 512 + tid;
        kreg[r] = *(const uint4*)(xtb + (size_t)(kbase + KT_ + (idx >> 5)) * C_ + (idx & 31) * 8);
    }
#pragma unroll
    for (int r = 0; r < 2; r++) {
        int idx = r * 512 + tid;
        vreg[r] = *(const uint4*)(gxb + (size_t)(idx >> 3) * N_ + kbase + KT_ + (idx & 7) * 8);
    }
    __syncthreads();                             // buf0 ready

    for (int it = 0; it < NITER; ++it) {
        const int cur = it & 1, nxt = cur ^ 1;

        if (it + 1 < NITER) {
#pragma unroll
            for (int r = 0; r < 4; r++) {
                int idx = r * 512 + tid;
                *(uint4*)&Ks[nxt][(idx >> 5) * KSTRIDE + (idx & 31) * 8] = kreg[r];
            }
#pragma unroll
            for (int r = 0; r < 2; r++) {
                int idx = r * 512 + tid;
                *(uint4*)&Vs[nxt][(idx >> 3) * VSTRIDE + (idx & 7) * 8] = vreg[r];
            }
        }
        if (it + 2 < NITER) {
            const int t0 = kbase + (it + 2) * KT_;
#pragma unroll
            for (int r = 0; r < 4; r++) {
                int idx = r * 512 + tid;
                kreg[r] = *(const uint4*)(xtb + (size_t)(t0 + (idx >> 5)) * C_ + (idx & 31) * 8);
            }
#pragma unroll
            for (int r = 0; r < 2; r++) {
                int idx = r * 512 + tid;
                vreg[r] = *(const uint4*)(gxb + (size_t)(idx >> 3) * N_ + t0 + (idx & 7) * 8);
            }
        }

        // ---- S = K.Q on this group's 32-m half: 16 mfma 32x32x16, 2 chains
        facc16 sa, sb;
#pragma unroll
        for (int r = 0; r < 16; r++) { sa[r] = 0.f; sb[r] = 0.f; }
#pragma unroll
        for (int kc = 0; kc < 8; kc++) {
            bfrag ka0 = *(const bfrag*)&Ks[cur][(32 * g + col) * KSTRIDE + (2 * kc) * 16 + h * 8];
            bfrag ka1 = *(const bfrag*)&Ks[cur][(32 * g + col) * KSTRIDE + (2 * kc + 1) * 16 + h * 8];
            sa = __builtin_amdgcn_mfma_f32_32x32x16_bf16(ka0, qb[2 * kc], sa, 0, 0, 0);
            sb = __builtin_amdgcn_mfma_f32_32x32x16_bf16(ka1, qb[2 * kc + 1], sb, 0, 0, 0);
        }
        facc16 sacc = sa + sb;
        // lane holds q = col (both h-halves same q), m_local = (r&3)+8*(r>>2)+4*h

        // ---- group-local online softmax (per-q state, halves agree) ----
        float mx = -INFINITY;
#pragma unroll
        for (int r = 0; r < 16; r++) mx = fmaxf(mx, sacc[r]);
        mx = fmaxf(mx, __shfl_xor(mx, 32, 64));
        float mn = fmaxf(mrun, mx);
        float alpha = __expf(mrun - mn);       // -inf -> 0 first iter
        mrun = mn;
        lrun *= alpha;
        if (__any(alpha != 1.f)) {
#pragma unroll
            for (int t = 0; t < 4; t++)
#pragma unroll
                for (int r = 0; r < 16; r++) yacc[t][r] *= alpha;
        }

        // ---- P = exp(S-m) in place, pack to Ps[q][m] (wave-private) ----
        {
            const int q = 32 * wq + col;
            float lsum = 0.f;
#pragma unroll
            for (int r = 0; r < 16; r++) {
                sacc[r] = __expf(sacc[r] - mrun);
                lsum += sacc[r];
            }
            lrun += lsum;
#pragma unroll
            for (int rq = 0; rq < 4; rq++) {
                unsigned lo = pack_bf16(sacc[4 * rq + 0], sacc[4 * rq + 1]);
                unsigned hi = pack_bf16(sacc[4 * rq + 2], sacc[4 * rq + 3]);
                unsigned long long pv = (unsigned long long)lo
                                      | ((unsigned long long)hi << 32);
                *(unsigned long long*)&Ps[q * VSTRIDE + 32 * g + 8 * rq + 4 * h] = pv;
            }
        }

        // ---- Yt += V.P over group's m-half: 8 mfma 32x32x16 ----
#pragma unroll
        for (int mc = 0; mc < 2; mc++) {
            bfrag pb = *(const bfrag*)&Ps[(32 * wq + col) * VSTRIDE + 32 * g + mc * 16 + h * 8];
#pragma unroll
            for (int ct = 0; ct < 4; ct++) {
                bfrag va = *(const bfrag*)&Vs[cur][(32 * ct + col) * VSTRIDE + 32 * g + mc * 16 + h * 8];
                yacc[ct] = __builtin_amdgcn_mfma_f32_32x32x16_bf16(va, pb, yacc[ct], 0, 0, 0);
            }
        }

        __syncthreads();   // buf[nxt] staged; buf[cur] reads done
    }

    // ---- epilogue: merge the two m-groups (split-K algebra), store ----
    lrun += __shfl_xor(lrun, 32, 64);

    float* PsF = (float*)Ps;          // Ps dead; 18432 B = 16 KB Ysc + 2 KB mlb
    float* Ysc = PsF;                 // [32 ci'][128 q]
    float* mlb = PsF + 4096;          // [2 g][128 q][2]

    const int q = 32 * wq + col;
    if (h == 0) {
        mlb[(g * 128 + q) * 2]     = mrun;
        mlb[(g * 128 + q) * 2 + 1] = lrun;
    }
    __syncthreads();
    float m0 = mlb[q * 2],           l0 = mlb[q * 2 + 1];
    float m1 = mlb[(128 + q) * 2],   l1 = mlb[(128 + q) * 2 + 1];
    float mm = fmaxf(m0, m1);
    float e0 = __expf(m0 - mm), e1 = __expf(m1 - mm);
    float lnew = e0 * l0 + e1 * l1;

#pragma unroll
    for (int ct = 0; ct < 4; ct++) {             // ci chunks of 32
        if (g == 1) {
#pragma unroll
            for (int r = 0; r < 16; r++) {
                int cl = (r & 3) + 8 * (r >> 2) + 4 * h;
                Ysc[cl * 128 + q] = e1 * yacc[ct][r];
            }
        }
        __syncthreads();
        if (g == 0) {
#pragma unroll
            for (int r = 0; r < 16; r++) {
                int cl = (r & 3) + 8 * (r >> 2) + 4 * h;
                float v = e0 * yacc[ct][r] + Ysc[cl * 128 + q];
                Yp[(((size_t)half * 4 + b) * CI_ + 32 * ct + cl) * N_ + n0 + q] = v;
            }
        }
        __syncthreads();
    }
    if (g == 0 && h == 0) {
        ml[(((size_t)half * 4 + b) * N_ + n0 + q) * 2]     = mm;
        ml[(((size_t)half * 4 + b) * N_ + n0 + q) * 2 + 1] = lnew;
    }
}

// ---------------- K4: merge split-K halves -> y fp32 (float4) ------------
__global__ __launch_bounds__(256) void merge(const float* __restrict__ Yp,
                                             const float* __restrict__ ml,
                                             float* __restrict__ y) {
    int n4 = blockIdx.x * 256 + threadIdx.x;
    int ci = blockIdx.y;
    int b  = blockIdx.z;
    int n  = n4 * 4;
    float4 a0 = *(const float4*)&ml[((size_t)b * N_ + n) * 2];
    float4 a1 = *(const float4*)&ml[((size_t)b * N_ + n + 2) * 2];
    float4 c0 = *(const float4*)&ml[(((size_t)4 + b) * N_ + n) * 2];
    float4 c1 = *(const float4*)&ml[(((size_t)4 + b) * N_ + n + 2) * 2];
    float m0[4] = {a0.x, a0.z, a1.x, a1.z};
    float l0[4] = {a0.y, a0.w, a1.y, a1.w};
    float m1[4] = {c0.x, c0.z, c1.x, c1.z};
    float l1[4] = {c0.y, c0.w, c1.y, c1.w};
    float w0[4], w1[4];
#pragma unroll
    for (int k = 0; k < 4; k++) {
        float mm = fmaxf(m0[k], m1[k]);
        float e0 = __expf(m0[k] - mm), e1 = __expf(m1[k] - mm);
        float inv = 1.f / (e0 * l0[k] + e1 * l1[k]);
        w0[k] = e0 * inv;
        w1[k] = e1 * inv;
    }
    size_t base = ((size_t)b * CI_ + ci) * N_ + n;
    float4 y0 = *(const float4*)&Yp[base];
    float4 y1 = *(const float4*)&Yp[(size_t)4 * CI_ * N_ + base];
    float4 o;
    o.x = w0[0] * y0.x + w1[0] * y1.x;
    o.y = w0[1] * y0.y + w1[1] * y1.y;
    o.z = w0[2] * y0.z + w1[2] * y1.z;
    o.w = w0[3] * y0.w + w1[3] * y1.w;
    *(float4*)&y[base] = o;
}

// ---------------- K5: W conv + BN stats (verbatim) -----------------------
__global__ __launch_bounds__(256) void wconv_stats(const float* __restrict__ y,
                                                   const float* __restrict__ Ww,
                                                   const float* __restrict__ Wb,
                                                   float* __restrict__ wy,
                                                   float* __restrict__ sums) {
    int n   = blockIdx.x * 256 + threadIdx.x;
    int co0 = blockIdx.y * 16;
    int b   = blockIdx.z;
    const float* yb = y + (size_t)b * CI_ * N_;
    float acc[16];
#pragma unroll
    for (int o = 0; o < 16; o++) acc[o] = Wb[co0 + o];
    for (int c0 = 0; c0 < CI_; c0 += 8) {
        float yv[8];
#pragma unroll
        for (int j = 0; j < 8; j++) yv[j] = yb[(c0 + j) * N_ + n];
#pragma unroll
        for (int o = 0; o < 16; o++) {
            const float* wr = Ww + (size_t)(co0 + o) * CI_ + c0;
#pragma unroll
            for (int j = 0; j < 8; j++) acc[o] += wr[j] * yv[j];
        }
    }
    float* wyb = wy + (size_t)b * C_ * N_;
#pragma unroll
    for (int o = 0; o < 16; o++) wyb[(co0 + o) * N_ + n] = acc[o];

    __shared__ float wred[32][4];
    int lane = threadIdx.x & 63, wid = threadIdx.x >> 6;
#pragma unroll
    for (int o = 0; o < 16; o++) {
        float s1 = acc[o], s2 = acc[o] * acc[o];
#pragma unroll
        for (int off = 32; off > 0; off >>= 1) {
            s1 += __shfl_down(s1, off, 64);
            s2 += __shfl_down(s2, off, 64);
        }
        if (lane == 0) { wred[o][wid] = s1; wred[16 + o][wid] = s2; }
    }
    __syncthreads();
    if (threadIdx.x < 32) {
        int qq = threadIdx.x;
        float t = wred[qq][0] + wred[qq][1] + wred[qq][2] + wred[qq][3];
        int o = qq & 15;
        if (qq < 16) atomicAdd(&sums[co0 + o], t);
        else         atomicAdd(&sums[256 + co0 + o], t);
    }
}

// ---------------- K6: BN finalize + residual (verbatim) ------------------
__global__ __launch_bounds__(256) void bn_finalize(float* __restrict__ wy,
                                                   const float* __restrict__ x,
                                                   const float* __restrict__ sums,
                                                   const float* __restrict__ gamma,
                                                   const float* __restrict__ beta,
                                                   float* __restrict__ out) {
    int n4 = blockIdx.x * 256 + threadIdx.x;
    int co = blockIdx.y;
    int b  = blockIdx.z;
    float cnt  = (float)(B_ * N_);
    float mean = sums[co] / cnt;
    float var  = sums[256 + co] / cnt - mean * mean;
    float sc   = rsqrtf(var + EPS_) * gamma[co];
    float bt   = beta[co];
    size_t idx = ((size_t)b * C_ + co) * N_ + (size_t)n4 * 4;
    float4 wv = *(const float4*)&wy[idx];
    float4 xv = *(const float4*)&x[idx];
    float4 o;
    o.x = (wv.x - mean) * sc + bt + xv.x;
    o.y = (wv.y - mean) * sc + bt + xv.y;
    o.z = (wv.z - mean) * sc + bt + xv.z;
    o.w = (wv.w - mean) * sc + bt + xv.w;
    *(float4*)&out[idx] = o;
}

extern "C" void kernel_launch(void* const* d_in, const int* in_sizes, int n_in,
                              void* d_out, int out_size, void* d_ws, size_t ws_size,
                              hipStream_t stream) {
    const float* x     = (const float*)d_in[0];
    const float* gw    = (const float*)d_in[1];
    const float* gb    = (const float*)d_in[2];
    const float* Ww    = (const float*)d_in[3];
    const float* Wb    = (const float*)d_in[4];
    const float* gamma = (const float*)d_in[5];
    const float* beta  = (const float*)d_in[6];
    float* out = (float*)d_out;
    float* ws  = (float*)d_ws;

    // ws (floats): total 7,406,080 = 29.6 MB (round-3 proven footprint)
    unsigned short* xt  = (unsigned short*)ws;              // 8 MB
    unsigned short* gxb = (unsigned short*)(ws + 2097152);  // 4 MB
    float* Yp   = ws + 3145728;                             // 16 MB
    float* ml   = ws + 7340032;                             // 256 KB
    float* sums = ws + 7405568;                             // 2 KB
    float* y    = ws;                                       // aliases xt (dead after attn)
    float* wy   = out;                                      // aliased onto d_out

    hipLaunchKernelGGL(make_xt, dim3(16, 32, 4), dim3(256), 0, stream, x, xt, sums);
    hipLaunchKernelGGL(gconv, dim3(16, 8, 4), dim3(256), 0, stream, x, gw, gb, gxb);
    hipLaunchKernelGGL(attn, dim3(256), dim3(512), 0, stream, xt, gxb, Yp, ml);
    hipLaunchKernelGGL(merge, dim3(4, 128, 4), dim3(256), 0, stream, Yp, ml, y);
    hipLaunchKernelGGL(wconv_stats, dim3(16, 16, 4), dim3(256), 0, stream, y, Ww, Wb, wy, sums);
    hipLaunchKernelGGL(bn_finalize, dim3(4, 256, 4), dim3(256), 0, stream, wy, x, sums, gamma, beta, out);
}